// Round 9
// baseline (106.241 us; speedup 1.0000x reference)
//
#include <hip/hip_runtime.h>
#include <stdint.h>

#define BATCH 2048
#define INF 1024
#define OUTF 1024
#define GRID_G 8
#define KTOT 9216   // INF + INF*GRID_G

#define BM 128
#define BN 128
#define BK 32
#define SK 8
#define KC (KTOT / SK)   // 1152
#define NKT (KC / BK)    // 36
#define MT (BATCH / BM)  // 16
#define NT (OUTF / BN)   // 8
#define CSLAB ((size_t)BATCH * OUTF)

typedef __attribute__((ext_vector_type(8))) short short8_t;
typedef __attribute__((ext_vector_type(4))) float f32x4_t;
typedef __attribute__((ext_vector_type(8))) unsigned short u16x8_t;

__device__ __forceinline__ unsigned short f2bf(float f) {
  unsigned int u = __float_as_uint(f);
  u += 0x7FFFu + ((u >> 16) & 1u);
  return (unsigned short)(u >> 16);
}

__device__ __forceinline__ void async16(void* lds, const void* g) {
  __builtin_amdgcn_global_load_lds(
      (const __attribute__((address_space(1))) void*)g,
      (__attribute__((address_space(3))) void*)lds, 16, 0, 0);
}

// Build W_cat[o][k]: k<1024 -> bf16(base_weight[o][k]); else bf16(coeff[o][k-1024])
__global__ __launch_bounds__(256) void build_w_kernel(
    const float* __restrict__ bw, const float* __restrict__ coeff,
    unsigned short* __restrict__ wc) {
  int id = blockIdx.x * 256 + threadIdx.x;  // one thread per 8 elements
  int row = id / (KTOT / 8);
  int k8 = id - row * (KTOT / 8);
  int k = k8 * 8;
  const float* src = (k < INF) ? (bw + (size_t)row * INF + k)
                               : (coeff + (size_t)row * (INF * GRID_G) + (k - INF));
  const float4* s4 = (const float4*)src;
  float4 a = s4[0], b = s4[1];
  u16x8_t v;
  v[0] = f2bf(a.x); v[1] = f2bf(a.y); v[2] = f2bf(a.z); v[3] = f2bf(a.w);
  v[4] = f2bf(b.x); v[5] = f2bf(b.y); v[6] = f2bf(b.z); v[7] = f2bf(b.w);
  *(u16x8_t*)(wc + (size_t)id * 8) = v;
}

// Build A_cat[b][k]: k<1024 -> bf16(x[b][k]); spline block: one-hot(idx)*bf16(0.1*w)
__global__ __launch_bounds__(256) void build_a_kernel(
    const float* __restrict__ x, const float* __restrict__ grid,
    unsigned short* __restrict__ ac) {
  __shared__ float sg[GRID_G + 1];
  if (threadIdx.x <= GRID_G) sg[threadIdx.x] = grid[threadIdx.x];
  __syncthreads();
  int id = blockIdx.x * 256 + threadIdx.x;  // one per (b,i)
  int b = id >> 10;
  int i = id & 1023;
  float xv = x[id];
  ac[(size_t)b * KTOT + i] = f2bf(xv);
  float xc = fminf(fmaxf(xv, -1.0f), 1.0f);
  int cnt = 0;
#pragma unroll
  for (int j = 0; j <= GRID_G; ++j) cnt += (xc >= sg[j]) ? 1 : 0;
  int idx = cnt - 1;
  idx = idx < 0 ? 0 : (idx > GRID_G - 1 ? GRID_G - 1 : idx);
  float left = sg[idx], right = sg[idx + 1];
  float denom = right - left;
  denom = (denom == 0.0f) ? 1.0f : denom;
  float w = (xc - left) / denom;
  unsigned short val = f2bf(0.1f * w);
  u16x8_t v;
#pragma unroll
  for (int g = 0; g < GRID_G; ++g) v[g] = (g == idx) ? val : (unsigned short)0;
  *(u16x8_t*)(ac + (size_t)b * KTOT + INF + (size_t)i * 8) = v;
}

// 128x128xBK32 split-K GEMM, 4 blocks/CU (cross-block latency hiding) +
// counted-vmcnt double-buffer pipeline (never drains vmcnt to 0 in steady
// state, unlike R4's __syncthreads which forced a full drain per iter).
//
// Per iter t (cur = t&1):
//   vmcnt(4)  [tile t's 4 loads done; tile t+1's 4 stay in flight]
//   s_barrier
//   8x ds_read_b128 (cur) ; 16 MFMA (setprio)
//   lgkmcnt(0) ; s_barrier       [all waves' reads of cur complete]
//   STAGE(cur, t+2)              [refill freed buffer; queue back to 8]
// Prologue stages tiles 0,1. Tile-t loads get ~1.5 iters + 3 other blocks of
// latency cover. Chunk-transposed 1KB LDS blocks: ds_read_b128 conflict-free.
__global__ __launch_bounds__(256, 4) void gemm_kernel(
    const unsigned short* __restrict__ A, const unsigned short* __restrict__ W,
    unsigned short* __restrict__ P) {
  __shared__ unsigned short As[2][BM * BK];  // 2 x 8 KB
  __shared__ unsigned short Bs[2][BN * BK];  // 2 x 8 KB

  int bid = blockIdx.x;
  int sk = bid & 7;            // XCD affinity: one sk-slab per XCD
  int t0 = bid >> 3;           // 0..127
  int mt = t0 >> 3;
  int nt = t0 & 7;

  int tid = threadIdx.x;
  int wave = tid >> 6;
  int lane = tid & 63;
  int wm = wave >> 1, wn = wave & 1;  // 2x2 wave grid, 64x64 per wave
  int lr = lane & 15, lk = lane >> 4;

  // chunk-transposed staging: 1KB block = 16 rows x 4 chunks(16B); within
  // block g, (row 16g+r, chunk k) -> physical chunk k*16+r. Source per lane:
  // row = 16*wave + (lane&15) (+64 for 2nd half), chunk = lane>>4.
  int srow = wave * 16 + (lane & 15);
  int scol = (lane >> 4) * 8;
  const unsigned short* gA  = A + (size_t)(mt * BM + srow) * KTOT + sk * KC + scol;
  const unsigned short* gA2 = gA + (size_t)64 * KTOT;
  const unsigned short* gB  = W + (size_t)(nt * BN + srow) * KTOT + sk * KC + scol;
  const unsigned short* gB2 = gB + (size_t)64 * KTOT;

  // frag read: row wm*64+mi*16+lr -> block wm*4+mi, offset lk*128+lr*8
  int rlo = lk * 128 + lr * 8;

  f32x4_t acc[4][4];
#pragma unroll
  for (int i2 = 0; i2 < 4; ++i2)
#pragma unroll
    for (int j2 = 0; j2 < 4; ++j2) acc[i2][j2] = f32x4_t{0.0f, 0.0f, 0.0f, 0.0f};

#define STAGE_AB(bf_, tt) { \
    int ko_ = (tt) * BK; \
    unsigned short* da_ = &As[bf_][wave * 512]; \
    async16(da_, gA + ko_); \
    async16(da_ + 2048, gA2 + ko_); \
    unsigned short* db_ = &Bs[bf_][wave * 512]; \
    async16(db_, gB + ko_); \
    async16(db_ + 2048, gB2 + ko_); }

  // prologue: tiles 0 and 1
  STAGE_AB(0, 0)
  STAGE_AB(1, 1)

  for (int t = 0; t < NKT; ++t) {
    int cur = t & 1;
    if (t + 1 < NKT) {
      asm volatile("s_waitcnt vmcnt(4)" ::: "memory");
    } else {
      asm volatile("s_waitcnt vmcnt(0)" ::: "memory");
    }
    __builtin_amdgcn_s_barrier();
    asm volatile("" ::: "memory");

    short8_t af[4], bf[4];
#pragma unroll
    for (int mi = 0; mi < 4; ++mi)
      af[mi] = *(const short8_t*)&As[cur][(wm * 4 + mi) * 512 + rlo];
#pragma unroll
    for (int ni = 0; ni < 4; ++ni)
      bf[ni] = *(const short8_t*)&Bs[cur][(wn * 4 + ni) * 512 + rlo];

    __builtin_amdgcn_s_setprio(1);
#pragma unroll
    for (int mi = 0; mi < 4; ++mi)
#pragma unroll
      for (int ni = 0; ni < 4; ++ni)
        acc[mi][ni] = __builtin_amdgcn_mfma_f32_16x16x32_bf16(af[mi], bf[ni], acc[mi][ni], 0, 0, 0);
    __builtin_amdgcn_s_setprio(0);

    asm volatile("s_waitcnt lgkmcnt(0)" ::: "memory");  // reads of cur drained
    __builtin_amdgcn_s_barrier();
    asm volatile("" ::: "memory");
    if (t + 2 < NKT) STAGE_AB(cur, t + 2)   // refill freed buffer
  }

  // epilogue: C/D col=lane&15 (n), row=(lane>>4)*4+reg (m); private bf16 slab
  unsigned short* slab = P + (size_t)sk * CSLAB;
#pragma unroll
  for (int mi = 0; mi < 4; ++mi) {
#pragma unroll
    for (int ni = 0; ni < 4; ++ni) {
      int col = nt * BN + wn * 64 + ni * 16 + lr;
#pragma unroll
      for (int r = 0; r < 4; ++r) {
        int rowm = mt * BM + wm * 64 + mi * 16 + lk * 4 + r;
        slab[(size_t)rowm * OUTF + col] = f2bf(acc[mi][ni][r]);
      }
    }
  }
}

// out[e] = sum_sk P[sk][e]; 8 elements/thread, fully overwrites d_out.
__global__ __launch_bounds__(256) void reduce_kernel(
    const unsigned short* __restrict__ P, float* __restrict__ out) {
  size_t base = ((size_t)blockIdx.x * 256 + threadIdx.x) * 8;
  float s[8];
#pragma unroll
  for (int j = 0; j < 8; ++j) s[j] = 0.0f;
#pragma unroll
  for (int k = 0; k < SK; ++k) {
    u16x8_t v = *(const u16x8_t*)(P + (size_t)k * CSLAB + base);
#pragma unroll
    for (int j = 0; j < 8; ++j)
      s[j] += __uint_as_float((unsigned int)v[j] << 16);
  }
  float4 lo = {s[0], s[1], s[2], s[3]};
  float4 hi = {s[4], s[5], s[6], s[7]};
  *(float4*)(out + base) = lo;
  *(float4*)(out + base + 4) = hi;
}

extern "C" void kernel_launch(void* const* d_in, const int* in_sizes, int n_in,
                              void* d_out, int out_size, void* d_ws, size_t ws_size,
                              hipStream_t stream) {
  const float* x = (const float*)d_in[0];
  const float* bw = (const float*)d_in[1];
  const float* coeff = (const float*)d_in[2];
  const float* grid = (const float*)d_in[3];
  float* out = (float*)d_out;

  unsigned short* Acat = (unsigned short*)d_ws;              // 37.75 MB
  unsigned short* Wcat = Acat + (size_t)BATCH * KTOT;        // 18.87 MB
  unsigned short* Part = Wcat + (size_t)OUTF * KTOT;         // 33.55 MB

  build_w_kernel<<<OUTF * (KTOT / 8) / 256, 256, 0, stream>>>(bw, coeff, Wcat);
  build_a_kernel<<<BATCH * INF / 256, 256, 0, stream>>>(x, grid, Acat);
  gemm_kernel<<<SK * MT * NT, 256, 0, stream>>>(Acat, Wcat, Part);
  reduce_kernel<<<(int)(CSLAB / 8 / 256), 256, 0, stream>>>(Part, out);
}

// Round 10
// 89.762 us; speedup vs baseline: 1.1836x; 1.1836x over previous
//
#include <hip/hip_runtime.h>
#include <stdint.h>

#define BATCH 2048
#define INF 1024
#define OUTF 1024
#define GRID_G 8
#define KTOT 9216   // INF + INF*GRID_G (Wcat layout)

// base GEMM (K=1024, bf16 dense)
#define BSK 4
#define BKC (INF / BSK)      // 256
#define BNKT (BKC / 32)      // 8 iters of BK=32
// spline GEMM (K_i=1024 i's = 8192 virtual K, packed one-hot A)
#define SSK 8
#define SIC (INF / SSK)      // 128 i per slab
#define SNKT (SIC / 8)       // 16 iters of 8 i (=64 virtual K)
#define NSLAB (BSK + SSK)    // 12 partial slabs
#define CSLAB ((size_t)BATCH * OUTF)

typedef __attribute__((ext_vector_type(8))) short short8_t;
typedef __attribute__((ext_vector_type(4))) float f32x4_t;
typedef __attribute__((ext_vector_type(8))) unsigned short u16x8_t;

__device__ __forceinline__ unsigned short f2bf(float f) {
  unsigned int u = __float_as_uint(f);
  u += 0x7FFFu + ((u >> 16) & 1u);
  return (unsigned short)(u >> 16);
}

__device__ __forceinline__ void async16(void* lds, const void* g) {
  __builtin_amdgcn_global_load_lds(
      (const __attribute__((address_space(1))) void*)g,
      (__attribute__((address_space(3))) void*)lds, 16, 0, 0);
}

// Expand packed (bf16 w | idx<<16) into the 8-element one-hot A fragment:
// frag[j] = (j==idx) ? w : 0, laid out as 4 u32 (two bf16 each).
__device__ __forceinline__ short8_t onehot_frag(unsigned int p) {
  unsigned int wlo = p & 0xFFFFu;
  unsigned int idx = p >> 16;
  unsigned int sel = (idx & 1u) ? (wlo << 16) : wlo;
  unsigned int jt = idx >> 1;
  union { unsigned int u[4]; short8_t s; } r;
  r.u[0] = (jt == 0u) ? sel : 0u;
  r.u[1] = (jt == 1u) ? sel : 0u;
  r.u[2] = (jt == 2u) ? sel : 0u;
  r.u[3] = (jt == 3u) ? sel : 0u;
  return r.s;
}

// Build W_cat[o][k]: k<1024 -> bf16(base_weight[o][k]); else bf16(coeff[o][k-1024])
__global__ __launch_bounds__(256) void build_w_kernel(
    const float* __restrict__ bw, const float* __restrict__ coeff,
    unsigned short* __restrict__ wc) {
  int id = blockIdx.x * 256 + threadIdx.x;  // one thread per 8 elements
  int row = id / (KTOT / 8);
  int k8 = id - row * (KTOT / 8);
  int k = k8 * 8;
  const float* src = (k < INF) ? (bw + (size_t)row * INF + k)
                               : (coeff + (size_t)row * (INF * GRID_G) + (k - INF));
  const float4* s4 = (const float4*)src;
  float4 a = s4[0], b = s4[1];
  u16x8_t v;
  v[0] = f2bf(a.x); v[1] = f2bf(a.y); v[2] = f2bf(a.z); v[3] = f2bf(a.w);
  v[4] = f2bf(b.x); v[5] = f2bf(b.y); v[6] = f2bf(b.z); v[7] = f2bf(b.w);
  *(u16x8_t*)(wc + (size_t)id * 8) = v;
}

// Per (b,i): Xbf = bf16(x); Apack = bf16(0.1*w) | (idx<<16)
__global__ __launch_bounds__(256) void build_apack_kernel(
    const float* __restrict__ x, const float* __restrict__ grid,
    unsigned short* __restrict__ xbf, unsigned int* __restrict__ ap) {
  __shared__ float sg[GRID_G + 1];
  if (threadIdx.x <= GRID_G) sg[threadIdx.x] = grid[threadIdx.x];
  __syncthreads();
  int id = blockIdx.x * 256 + threadIdx.x;
  float xv = x[id];
  xbf[id] = f2bf(xv);
  float xc = fminf(fmaxf(xv, -1.0f), 1.0f);
  int cnt = 0;
#pragma unroll
  for (int j = 0; j <= GRID_G; ++j) cnt += (xc >= sg[j]) ? 1 : 0;
  int idx = cnt - 1;
  idx = idx < 0 ? 0 : (idx > GRID_G - 1 ? GRID_G - 1 : idx);
  float left = sg[idx], right = sg[idx + 1];
  float denom = right - left;
  denom = (denom == 0.0f) ? 1.0f : denom;
  float w = (xc - left) / denom;
  ap[id] = (unsigned int)f2bf(0.1f * w) | ((unsigned int)idx << 16);
}

// Base GEMM: 128x128, BK=32, SK=4, R4-proven loop (1 __syncthreads/iter, dbuf,
// stage-after-sync), chunk-transposed LDS (16-row x 4-chunk units; phys chunk
// = k*16+r) -> conflict-free ds_read_b128 (verified 0 in R6/R7/R9).
__global__ __launch_bounds__(256, 4) void base_gemm_kernel(
    const unsigned short* __restrict__ Xb, const unsigned short* __restrict__ Wc,
    unsigned short* __restrict__ P) {
  __shared__ unsigned short As[2][128 * 32];
  __shared__ unsigned short Bs[2][128 * 32];

  int bid = blockIdx.x;
  int sk = bid & 3;
  int t0 = bid >> 2;           // 0..127
  int mt = t0 >> 3, nt = t0 & 7;

  int tid = threadIdx.x, wave = tid >> 6, lane = tid & 63;
  int wm = wave >> 1, wn = wave & 1;
  int lr = lane & 15, lk = lane >> 4;

  int srow = wave * 16 + (lane & 15);
  int scol = (lane >> 4) * 8;
  const unsigned short* gA  = Xb + (size_t)(mt * 128 + srow) * INF + sk * BKC + scol;
  const unsigned short* gA2 = gA + (size_t)64 * INF;
  const unsigned short* gB  = Wc + (size_t)(nt * 128 + srow) * KTOT + sk * BKC + scol;
  const unsigned short* gB2 = gB + (size_t)64 * KTOT;
  int rlo = lk * 128 + lr * 8;

  f32x4_t acc[4][4];
#pragma unroll
  for (int i2 = 0; i2 < 4; ++i2)
#pragma unroll
    for (int j2 = 0; j2 < 4; ++j2) acc[i2][j2] = f32x4_t{0.f, 0.f, 0.f, 0.f};

#define BSTAGE(b_, tt) { \
    int ko_ = (tt) * 32; \
    unsigned short* da_ = &As[b_][wave * 512]; \
    async16(da_, gA + ko_); async16(da_ + 2048, gA2 + ko_); \
    unsigned short* db_ = &Bs[b_][wave * 512]; \
    async16(db_, gB + ko_); async16(db_ + 2048, gB2 + ko_); }

  BSTAGE(0, 0)
  for (int t = 0; t < BNKT; ++t) {
    int cur = t & 1;
    __syncthreads();
    if (t + 1 < BNKT) BSTAGE(cur ^ 1, t + 1)
    short8_t af[4], bf[4];
#pragma unroll
    for (int mi = 0; mi < 4; ++mi)
      af[mi] = *(const short8_t*)&As[cur][(wm * 4 + mi) * 512 + rlo];
#pragma unroll
    for (int ni = 0; ni < 4; ++ni)
      bf[ni] = *(const short8_t*)&Bs[cur][(wn * 4 + ni) * 512 + rlo];
    __builtin_amdgcn_s_setprio(1);
#pragma unroll
    for (int mi = 0; mi < 4; ++mi)
#pragma unroll
      for (int ni = 0; ni < 4; ++ni)
        acc[mi][ni] = __builtin_amdgcn_mfma_f32_16x16x32_bf16(af[mi], bf[ni], acc[mi][ni], 0, 0, 0);
    __builtin_amdgcn_s_setprio(0);
  }

  unsigned short* slab = P + (size_t)sk * CSLAB;
#pragma unroll
  for (int mi = 0; mi < 4; ++mi)
#pragma unroll
    for (int ni = 0; ni < 4; ++ni) {
      int col = nt * 128 + wn * 64 + ni * 16 + lr;
#pragma unroll
      for (int r = 0; r < 4; ++r) {
        int rowm = mt * 128 + wm * 64 + mi * 16 + lk * 4 + r;
        slab[(size_t)rowm * OUTF + col] = f2bf(acc[mi][ni][r]);
      }
    }
}

// Spline GEMM: 128x128 output tile, 64 virtual K (=8 i) per iter, SK=8.
// A side is PACKED (u32/i): one-hot fragments built in-register (onehot_frag)
// -> A staging 4KB/iter instead of 16KB, LDS dbuf 40KB -> 4 blocks/CU with
// half the barriers per virtual K of the R4 kernel.
// B LDS: 8-row x 8-chunk 1KB units, phys chunk = c*8+r -> conflict-free b128.
__global__ __launch_bounds__(256, 4) void spline_gemm_kernel(
    const unsigned int* __restrict__ Ap, const unsigned short* __restrict__ Wc,
    unsigned short* __restrict__ P) {
  __shared__ unsigned int Aps[2][128 * 8];     // 2 x 4 KB
  __shared__ unsigned short Bs[2][128 * 64];   // 2 x 16 KB

  int bid = blockIdx.x;
  int sk = bid & 7;            // XCD<->slab affinity
  int t0 = bid >> 3;           // 0..127
  int mt = t0 >> 3, nt = t0 & 7;

  int tid = threadIdx.x, wave = tid >> 6, lane = tid & 63;
  int wm = wave >> 1, wn = wave & 1;
  int lr = lane & 15, lk = lane >> 4;

  // A staging: wave w covers rows 32w..32w+31 (32B/row); lane l -> row
  // 32w+(l>>1), half (l&1) (16B = 4 u32)
  const unsigned int* gAp = Ap + (size_t)(mt * 128 + wave * 32 + (lane >> 1)) * INF
                            + sk * SIC + (lane & 1) * 4;
  // B staging: unit u = wave*4+q = rows 8u..8u+7; lane l -> row 8u+(l&7),
  // chunk l>>3 (16B). Source col base: spline region starts at Wcat col 1024.
  const unsigned short* gB = Wc + (size_t)(nt * 128 + wave * 32 + (lane & 7)) * KTOT
                             + INF + sk * (SIC * 8) + (lane >> 3) * 8;
  const size_t q8 = (size_t)8 * KTOT;

  f32x4_t acc[4][4];
#pragma unroll
  for (int i2 = 0; i2 < 4; ++i2)
#pragma unroll
    for (int j2 = 0; j2 < 4; ++j2) acc[i2][j2] = f32x4_t{0.f, 0.f, 0.f, 0.f};

#define SSTAGE(b_, tt) { \
    async16(&Aps[b_][wave * 256], gAp + (tt) * 8); \
    unsigned short* db_ = &Bs[b_][wave * 2048]; \
    async16(db_,        gB + 0 * q8 + (tt) * 64); \
    async16(db_ + 512,  gB + 1 * q8 + (tt) * 64); \
    async16(db_ + 1024, gB + 2 * q8 + (tt) * 64); \
    async16(db_ + 1536, gB + 3 * q8 + (tt) * 64); }

  SSTAGE(0, 0)
  for (int t = 0; t < SNKT; ++t) {
    int cur = t & 1;
    __syncthreads();
    if (t + 1 < SNKT) SSTAGE(cur ^ 1, t + 1)
#pragma unroll
    for (int ks = 0; ks < 2; ++ks) {
      // B frags: row wn*64+nf*16+lr, chunk c=ks*4+lk ->
      // elem = unit*512 + c*64 + (lr&7)*8, unit = wn*8+nf*2+(lr>>3)
      short8_t bf[4];
#pragma unroll
      for (int nf = 0; nf < 4; ++nf)
        bf[nf] = *(const short8_t*)&Bs[cur][(wn * 8 + nf * 2 + (lr >> 3)) * 512
                                            + (ks * 4 + lk) * 64 + (lr & 7) * 8];
      // A pairs + one-hot fragments: row wm*64+mi*16+lr, i_local = ks*4+lk
      unsigned int pr[4];
#pragma unroll
      for (int mi = 0; mi < 4; ++mi)
        pr[mi] = Aps[cur][(wm * 64 + mi * 16 + lr) * 8 + ks * 4 + lk];
      short8_t af[4];
#pragma unroll
      for (int mi = 0; mi < 4; ++mi) af[mi] = onehot_frag(pr[mi]);
      __builtin_amdgcn_s_setprio(1);
#pragma unroll
      for (int mi = 0; mi < 4; ++mi)
#pragma unroll
        for (int nf = 0; nf < 4; ++nf)
          acc[mi][nf] = __builtin_amdgcn_mfma_f32_16x16x32_bf16(af[mi], bf[nf], acc[mi][nf], 0, 0, 0);
      __builtin_amdgcn_s_setprio(0);
    }
  }

  unsigned short* slab = P + (size_t)(BSK + sk) * CSLAB;
#pragma unroll
  for (int mi = 0; mi < 4; ++mi)
#pragma unroll
    for (int ni = 0; ni < 4; ++ni) {
      int col = nt * 128 + wn * 64 + ni * 16 + lr;
#pragma unroll
      for (int r = 0; r < 4; ++r) {
        int rowm = mt * 128 + wm * 64 + mi * 16 + lk * 4 + r;
        slab[(size_t)rowm * OUTF + col] = f2bf(acc[mi][ni][r]);
      }
    }
}

// out[e] = sum over 12 partial slabs; 8 elements/thread, overwrites d_out.
__global__ __launch_bounds__(256) void reduce_kernel(
    const unsigned short* __restrict__ P, float* __restrict__ out) {
  size_t base = ((size_t)blockIdx.x * 256 + threadIdx.x) * 8;
  float s[8];
#pragma unroll
  for (int j = 0; j < 8; ++j) s[j] = 0.0f;
#pragma unroll
  for (int k = 0; k < NSLAB; ++k) {
    u16x8_t v = *(const u16x8_t*)(P + (size_t)k * CSLAB + base);
#pragma unroll
    for (int j = 0; j < 8; ++j)
      s[j] += __uint_as_float((unsigned int)v[j] << 16);
  }
  float4 lo = {s[0], s[1], s[2], s[3]};
  float4 hi = {s[4], s[5], s[6], s[7]};
  *(float4*)(out + base) = lo;
  *(float4*)(out + base + 4) = hi;
}

extern "C" void kernel_launch(void* const* d_in, const int* in_sizes, int n_in,
                              void* d_out, int out_size, void* d_ws, size_t ws_size,
                              hipStream_t stream) {
  const float* x = (const float*)d_in[0];
  const float* bw = (const float*)d_in[1];
  const float* coeff = (const float*)d_in[2];
  const float* grid = (const float*)d_in[3];
  float* out = (float*)d_out;

  unsigned short* Wcat = (unsigned short*)d_ws;              // 18.87 MB
  unsigned short* Xbf  = Wcat + (size_t)OUTF * KTOT;         //  4.19 MB
  unsigned int*   Apack = (unsigned int*)(Xbf + (size_t)BATCH * INF);  // 8.39 MB
  unsigned short* Part = (unsigned short*)(Apack + (size_t)BATCH * INF); // 12 x 4.19 MB

  build_w_kernel<<<OUTF * (KTOT / 8) / 256, 256, 0, stream>>>(bw, coeff, Wcat);
  build_apack_kernel<<<BATCH * INF / 256, 256, 0, stream>>>(x, grid, Xbf, Apack);
  base_gemm_kernel<<<BSK * 16 * 8, 256, 0, stream>>>(Xbf, Wcat, Part);
  spline_gemm_kernel<<<SSK * 16 * 8, 256, 0, stream>>>(Apack, Wcat, Part);
  reduce_kernel<<<(int)(CSLAB / 8 / 256), 256, 0, stream>>>(Part, out);
}

// Round 11
// 71.328 us; speedup vs baseline: 1.4895x; 1.2584x over previous
//
#include <hip/hip_runtime.h>
#include <stdint.h>

#define BATCH 2048
#define INF 1024
#define OUTF 1024
#define GRID_G 8
#define KTOT 9216   // INF + INF*GRID_G (Wcat layout)

#define SK 8
#define MTT 8            // BATCH/256
#define NTT 4            // OUTF/256
#define CSLAB ((size_t)BATCH * OUTF)

typedef __attribute__((ext_vector_type(8))) short short8_t;
typedef __attribute__((ext_vector_type(4))) float f32x4_t;
typedef __attribute__((ext_vector_type(8))) unsigned short u16x8_t;

__device__ __forceinline__ unsigned short f2bf(float f) {
  unsigned int u = __float_as_uint(f);
  u += 0x7FFFu + ((u >> 16) & 1u);
  return (unsigned short)(u >> 16);
}

__device__ __forceinline__ void async16(void* lds, const void* g) {
  __builtin_amdgcn_global_load_lds(
      (const __attribute__((address_space(1))) void*)g,
      (__attribute__((address_space(3))) void*)lds, 16, 0, 0);
}

// frag[j] = (j==idx) ? w : 0 over 8 bf16, from packed (bf16 w | idx<<16)
__device__ __forceinline__ short8_t onehot_frag(unsigned int p) {
  unsigned int wlo = p & 0xFFFFu;
  unsigned int idx = p >> 16;
  unsigned int sel = (idx & 1u) ? (wlo << 16) : wlo;
  unsigned int jt = idx >> 1;
  union { unsigned int u[4]; short8_t s; } r;
  r.u[0] = (jt == 0u) ? sel : 0u;
  r.u[1] = (jt == 1u) ? sel : 0u;
  r.u[2] = (jt == 2u) ? sel : 0u;
  r.u[3] = (jt == 3u) ? sel : 0u;
  return r.s;
}

// Build W_cat[o][k]: k<1024 -> bf16(base_weight[o][k]); else bf16(coeff[o][k-1024])
__global__ __launch_bounds__(256) void build_w_kernel(
    const float* __restrict__ bw, const float* __restrict__ coeff,
    unsigned short* __restrict__ wc) {
  int id = blockIdx.x * 256 + threadIdx.x;
  int row = id / (KTOT / 8);
  int k8 = id - row * (KTOT / 8);
  int k = k8 * 8;
  const float* src = (k < INF) ? (bw + (size_t)row * INF + k)
                               : (coeff + (size_t)row * (INF * GRID_G) + (k - INF));
  const float4* s4 = (const float4*)src;
  float4 a = s4[0], b = s4[1];
  u16x8_t v;
  v[0] = f2bf(a.x); v[1] = f2bf(a.y); v[2] = f2bf(a.z); v[3] = f2bf(a.w);
  v[4] = f2bf(b.x); v[5] = f2bf(b.y); v[6] = f2bf(b.z); v[7] = f2bf(b.w);
  *(u16x8_t*)(wc + (size_t)id * 8) = v;
}

// Per (b,i): Xbf = bf16(x); Apack = bf16(0.1*w) | (idx<<16)
__global__ __launch_bounds__(256) void build_apack_kernel(
    const float* __restrict__ x, const float* __restrict__ grid,
    unsigned short* __restrict__ xbf, unsigned int* __restrict__ ap) {
  __shared__ float sg[GRID_G + 1];
  if (threadIdx.x <= GRID_G) sg[threadIdx.x] = grid[threadIdx.x];
  __syncthreads();
  int id = blockIdx.x * 256 + threadIdx.x;
  float xv = x[id];
  xbf[id] = f2bf(xv);
  float xc = fminf(fmaxf(xv, -1.0f), 1.0f);
  int cnt = 0;
#pragma unroll
  for (int j = 0; j <= GRID_G; ++j) cnt += (xc >= sg[j]) ? 1 : 0;
  int idx = cnt - 1;
  idx = idx < 0 ? 0 : (idx > GRID_G - 1 ? GRID_G - 1 : idx);
  float left = sg[idx], right = sg[idx + 1];
  float denom = right - left;
  denom = (denom == 0.0f) ? 1.0f : denom;
  float w = (xc - left) / denom;
  ap[id] = (unsigned int)f2bf(0.1f * w) | ((unsigned int)idx << 16);
}

// Fused 256x256 split-K GEMM (R5's proven 4-phase schedule, unchanged for the
// 2 dense base tiles; 16 spline tiles use packed-A with in-reg one-hot expand).
// Per sk-slab: KC = 128 base k (tiles 0,1) + 128 i = 1024 virtual k (tiles
// 2..17). B = Wcat cols [sk*128, +128) then [1024+sk*1024, +1024).
//
// Load-queue audit (per wave; async16 counts):
//   prologue: A0d,B0,A1d,B1 of t0 (8)          gates t0: (4,4)  [R5 exact]
//   t0 stages t1 dense: ph0 A0d(2) ph1 B0(2) ph2 A1d(2) ph3 B1(2)
//   t1 stages t2 spline: ph0 APK(1) ph1 B0(2) ph2 B1(2)   gates t1: (4,3)
//   spline t stages t+1: ph0 APK(1) ph1 B0(2) ph2 B1(2)   gates: (2, pf?3:0)
//   e.g. steady gate0: outstanding {APK,B0,B1}(t)=5, need APK+B0 -> vmcnt(2).
// Buffer-reuse safety: every region staged in tile t was last read in tile
// t-1, whose reads precede t's gate0 s_barrier in all waves.
// LDS: LA/LB[2][2][256x32] chunk-transposed (conflict-free b128, R6-verified);
// APK[c] (8 KB u32 [256][8]) overlays LA[c][0] (dense-A dead during spline).
__global__ __launch_bounds__(512, 2) void fused_gemm_kernel(
    const unsigned short* __restrict__ Xb, const unsigned int* __restrict__ Ap,
    const unsigned short* __restrict__ Wc, unsigned short* __restrict__ P) {
  __shared__ unsigned short LA[2][2][256 * 32];  // 64 KB
  __shared__ unsigned short LB[2][2][256 * 32];  // 64 KB

  int bid = blockIdx.x;
  int sk = bid & 7;          // XCD affinity
  int t0i = bid >> 3;        // 0..31
  int mt = t0i >> 2, nt = t0i & 3;

  int tid = threadIdx.x, wave = tid >> 6, lane = tid & 63;
  int wr = wave >> 2, wc = wave & 3;   // 2x4 wave grid; per-wave C = 128x64
  int lr = lane & 15, lk = lane >> 4;
  int rlo = lk * 128 + lr * 8;         // chunk-transposed read offset

  // dense staging source (chunk-transpose): lane -> row wave*16+(l&15), chunk l>>4
  int srow = wave * 16 + (lane & 15);
  int scol = ((lane >> 4) & 3) * 8;
  const unsigned short* gXA  = Xb + (size_t)(mt * 256 + srow) * INF + sk * 128 + scol;
  const unsigned short* gXA2 = gXA + (size_t)128 * INF;
  const unsigned short* gB   = Wc + (size_t)(nt * 256 + srow) * KTOT + scol;
  const unsigned short* gB2  = gB + (size_t)128 * KTOT;
  // packed-A source: lane l -> row wave*32+(l>>1), 4 u32 at iword (l&1)*4
  const unsigned int* gAP = Ap + (size_t)(mt * 256 + wave * 32 + (lane >> 1)) * INF
                            + sk * 128 + (lane & 1) * 4;

  unsigned int* APK0 = (unsigned int*)&LA[0][0][0];
  unsigned int* APK1 = (unsigned int*)&LA[1][0][0];

  const int CB = sk * 128;           // base col range base
  const int CS = 1024 + sk * 1024;   // spline col range base

  f32x4_t acc[2][4][4];
#pragma unroll
  for (int ch = 0; ch < 2; ++ch)
#pragma unroll
    for (int mf = 0; mf < 4; ++mf)
#pragma unroll
      for (int nf = 0; nf < 4; ++nf) acc[ch][mf][nf] = f32x4_t{0.f, 0.f, 0.f, 0.f};

#define VMW(N) asm volatile("s_waitcnt vmcnt(" #N ")" ::: "memory")
#define BARR() { __builtin_amdgcn_s_barrier(); asm volatile("" ::: "memory"); }
#define STAGE_XA(nb, ks, colofs) { unsigned short* d_ = &LA[nb][ks][wave * 512]; \
    async16(d_, gXA + (colofs) + (ks) * 32); \
    async16(d_ + 4096, gXA2 + (colofs) + (ks) * 32); }
#define STAGE_B(nb, ks, colofs) { unsigned short* d_ = &LB[nb][ks][wave * 512]; \
    async16(d_, gB + (colofs) + (ks) * 32); \
    async16(d_ + 4096, gB2 + (colofs) + (ks) * 32); }
#define STAGE_APK(APKn, tt) { async16((void*)((APKn) + wave * 256), gAP + ((tt) - 2) * 8); }
#define DSR_A(af_, CC, ks, ch) { _Pragma("unroll") for (int mf = 0; mf < 4; ++mf) \
    af_[mf] = *(const short8_t*)&LA[CC][ks][(wr * 8 + (ch) * 4 + mf) * 512 + rlo]; }
#define DSR_B(bf_, CC, ks) { _Pragma("unroll") for (int nf = 0; nf < 4; ++nf) \
    bf_[nf] = *(const short8_t*)&LB[CC][ks][(wc * 4 + nf) * 512 + rlo]; }
#define PRD(pr_, APKc, ks, ch) { _Pragma("unroll") for (int mf = 0; mf < 4; ++mf) \
    pr_[mf] = (APKc)[(wr * 128 + (ch) * 64 + mf * 16 + lr) * 8 + (ks) * 4 + lk]; }
#define EXPAND(af_, pr_) { _Pragma("unroll") for (int mf = 0; mf < 4; ++mf) \
    af_[mf] = onehot_frag(pr_[mf]); }
#define MFMA16(CH, af_, bf_) { __builtin_amdgcn_s_setprio(1); \
    _Pragma("unroll") for (int mf = 0; mf < 4; ++mf) \
    _Pragma("unroll") for (int nf = 0; nf < 4; ++nf) \
      acc[CH][mf][nf] = __builtin_amdgcn_mfma_f32_16x16x32_bf16( \
          af_[mf], bf_[nf], acc[CH][mf][nf], 0, 0, 0); \
    __builtin_amdgcn_s_setprio(0); }

  // prologue: tile0 (base) into buf0; order A0,B0,A1,B1
  STAGE_XA(0, 0, 0) STAGE_B(0, 0, CB) STAGE_XA(0, 1, 0) STAGE_B(0, 1, CB)

  { // tile0: base, c=0; stages t1(base)->buf1
    short8_t af[4], bf[4];
    VMW(4); BARR();
    DSR_A(af, 0, 0, 0) DSR_B(bf, 0, 0)
    STAGE_XA(1, 0, 64)
    MFMA16(0, af, bf)
    DSR_A(af, 0, 0, 1)
    STAGE_B(1, 0, CB + 64)
    MFMA16(1, af, bf)
    VMW(4); BARR();
    DSR_A(af, 0, 1, 0) DSR_B(bf, 0, 1)
    STAGE_XA(1, 1, 64)
    MFMA16(0, af, bf)
    DSR_A(af, 0, 1, 1)
    STAGE_B(1, 1, CB + 64)
    MFMA16(1, af, bf)
  }
  { // tile1: base, c=1; stages t2(spline)->buf0: APK@ph0, B0@ph1, B1@ph2
    short8_t af[4], bf[4];
    VMW(4); BARR();
    DSR_A(af, 1, 0, 0) DSR_B(bf, 1, 0)
    STAGE_APK(APK0, 2)
    MFMA16(0, af, bf)
    DSR_A(af, 1, 0, 1)
    STAGE_B(0, 0, CS)
    MFMA16(1, af, bf)
    VMW(3); BARR();
    DSR_A(af, 1, 1, 0) DSR_B(bf, 1, 1)
    STAGE_B(0, 1, CS)
    MFMA16(0, af, bf)
    DSR_A(af, 1, 1, 1)
    MFMA16(1, af, bf)
  }
  // spline tiles t=2..17
  for (int t = 2; t < 18; ++t) {
    int c = t & 1;
    unsigned int* APKc = c ? APK1 : APK0;
    unsigned int* APKn = c ? APK0 : APK1;
    int nb = c ^ 1;
    bool pf = t < 17;
    int cs = CS + (t - 1) * 64;   // (t+1-2)*64
    short8_t af[4], bf[4];
    unsigned int pr[4];
    VMW(2); BARR();
    PRD(pr, APKc, 0, 0) DSR_B(bf, c, 0)
    if (pf) STAGE_APK(APKn, t + 1)
    EXPAND(af, pr) MFMA16(0, af, bf)
    PRD(pr, APKc, 0, 1)
    if (pf) STAGE_B(nb, 0, cs)
    EXPAND(af, pr) MFMA16(1, af, bf)
    if (pf) { VMW(3); } else { VMW(0); }
    BARR();
    PRD(pr, APKc, 1, 0) DSR_B(bf, c, 1)
    if (pf) STAGE_B(nb, 1, cs)
    EXPAND(af, pr) MFMA16(0, af, bf)
    PRD(pr, APKc, 1, 1)
    EXPAND(af, pr) MFMA16(1, af, bf)
  }

  // epilogue: C/D col=lane&15 (n), row=(lane>>4)*4+reg (m); private bf16 slab
  unsigned short* slab = P + (size_t)sk * CSLAB;
#pragma unroll
  for (int ch = 0; ch < 2; ++ch)
#pragma unroll
    for (int mf = 0; mf < 4; ++mf)
#pragma unroll
      for (int nf = 0; nf < 4; ++nf) {
        int col = nt * 256 + wc * 64 + nf * 16 + lr;
        int rowb = mt * 256 + wr * 128 + ch * 64 + mf * 16 + lk * 4;
#pragma unroll
        for (int r = 0; r < 4; ++r)
          slab[(size_t)(rowb + r) * OUTF + col] = f2bf(acc[ch][mf][nf][r]);
      }
}

// out[e] = sum over 8 partial slabs; 8 elements/thread, overwrites d_out.
__global__ __launch_bounds__(256) void reduce_kernel(
    const unsigned short* __restrict__ P, float* __restrict__ out) {
  size_t base = ((size_t)blockIdx.x * 256 + threadIdx.x) * 8;
  float s[8];
#pragma unroll
  for (int j = 0; j < 8; ++j) s[j] = 0.0f;
#pragma unroll
  for (int k = 0; k < SK; ++k) {
    u16x8_t v = *(const u16x8_t*)(P + (size_t)k * CSLAB + base);
#pragma unroll
    for (int j = 0; j < 8; ++j)
      s[j] += __uint_as_float((unsigned int)v[j] << 16);
  }
  float4 lo = {s[0], s[1], s[2], s[3]};
  float4 hi = {s[4], s[5], s[6], s[7]};
  *(float4*)(out + base) = lo;
  *(float4*)(out + base + 4) = hi;
}

extern "C" void kernel_launch(void* const* d_in, const int* in_sizes, int n_in,
                              void* d_out, int out_size, void* d_ws, size_t ws_size,
                              hipStream_t stream) {
  const float* x = (const float*)d_in[0];
  const float* bw = (const float*)d_in[1];
  const float* coeff = (const float*)d_in[2];
  const float* grid = (const float*)d_in[3];
  float* out = (float*)d_out;

  unsigned short* Wcat = (unsigned short*)d_ws;                        // 18.87 MB
  unsigned short* Xbf  = Wcat + (size_t)OUTF * KTOT;                   //  4.19 MB
  unsigned int*   Apack = (unsigned int*)(Xbf + (size_t)BATCH * INF);  //  8.39 MB
  unsigned short* Part = (unsigned short*)(Apack + (size_t)BATCH * INF); // 8 x 4.19 MB

  build_w_kernel<<<OUTF * (KTOT / 8) / 256, 256, 0, stream>>>(bw, coeff, Wcat);
  build_apack_kernel<<<BATCH * INF / 256, 256, 0, stream>>>(x, grid, Xbf, Apack);
  fused_gemm_kernel<<<SK * MTT * NTT, 512, 0, stream>>>(Xbf, Apack, Wcat, Part);
  reduce_kernel<<<(int)(CSLAB / 8 / 256), 256, 0, stream>>>(Part, out);
}